// Round 13
// baseline (309.132 us; speedup 1.0000x reference)
//
#include <hip/hip_runtime.h>
#include <hip/hip_bf16.h>
#include <stdint.h>

#define B_ 256
#define H_ 4096
#define K_ 32768   // V*N = 1024*32

typedef __attribute__((ext_vector_type(8))) short bf16x8;
typedef __attribute__((ext_vector_type(4))) float f32x4;

__device__ __forceinline__ unsigned short f2bf(float x) {
    union { float f; unsigned int u; } c; c.f = x;
    unsigned int r = c.u + 0x7FFFu + ((c.u >> 16) & 1u);  // RNE
    return (unsigned short)(r >> 16);
}

__device__ __forceinline__ short bfc(float x) {
    __hip_bfloat16 h = __float2bfloat16(x);
    union { __hip_bfloat16 h; short s; } c; c.h = h;
    return c.s;
}

__device__ __forceinline__ float softplus_f(float x) {
    return fmaxf(x, 0.0f) + log1pf(expf(-fabsf(x)));
}

// ---------------- Kernel A: v fp32->bf16 + vt[b] = dot(v[b,:], b_v) ----------------
__global__ __launch_bounds__(256) void prep_kernel(
    const float* __restrict__ v, const float* __restrict__ bv,
    __hip_bfloat16* __restrict__ vbf, float* __restrict__ vt)
{
    const int b = blockIdx.x;
    const int t = threadIdx.x;
    const float* vr = v + (size_t)b * K_;
    unsigned short* dr = (unsigned short*)(vbf + (size_t)b * K_);
    float acc = 0.f;
    for (int i = t * 8; i < K_; i += 256 * 8) {
        float4 x0 = *(const float4*)(vr + i);
        float4 x1 = *(const float4*)(vr + i + 4);
        float4 b0 = *(const float4*)(bv + i);
        float4 b1 = *(const float4*)(bv + i + 4);
        acc += x0.x*b0.x + x0.y*b0.y + x0.z*b0.z + x0.w*b0.w
             + x1.x*b1.x + x1.y*b1.y + x1.z*b1.z + x1.w*b1.w;
        ushort4 u0, u1;
        u0.x = f2bf(x0.x); u0.y = f2bf(x0.y); u0.z = f2bf(x0.z); u0.w = f2bf(x0.w);
        u1.x = f2bf(x1.x); u1.y = f2bf(x1.y); u1.z = f2bf(x1.z); u1.w = f2bf(x1.w);
        *(ushort4*)(dr + i)     = u0;
        *(ushort4*)(dr + i + 4) = u1;
    }
    __shared__ float sm[256];
    sm[t] = acc;
    __syncthreads();
    for (int s = 128; s > 0; s >>= 1) {
        if (t < s) sm[t] += sm[t + s];
        __syncthreads();
    }
    if (t == 0) vt[b] = sm[0];
}

// ---------------- Kernel B: small-block high-TLP split-K GEMM ----------------
// BM=256 BN=32 BK=64, KS=8 (sidx = bid%8 == XCD -> v slice L2-resident).
// 256 threads = 4 waves, each 64M x 32N (acc[4][2] = 32 VGPR). Grid 1024 =
// 4 independent blocks/CU (16 waves, the 65..128-VGPR occupancy cap; LDS
// 4 x 32KB = 128KB). Latency hiding comes from cross-block TLP, not from a
// single fat block: barriers are 4-wave and per-block.
// W fp32 -> depth-4 8KB LDS ring via global_load_lds, dist-2 prefetch,
// XOR-(row&15) pre-swizzled source + swizzled ds_read_b128 (2-way = free).
// A (v bf16) global->reg double-buffered.
//
// vmem FIFO invariant (per body issue order: A(t+1) x8, W(t+2) x2):
//   entering body t: [A(t)8, W(t+1)2]
//   after issues:    [A(t)8, W(t+1)2, A(t+1)8, W(t+2)2] = 20
//   compute A(t)-wait = vmcnt(12) (compiler-exact; keeps W(t+1) in flight)
//   pre-barrier vmcnt(10): drains W(t+1) (slot t+1 read next body) ->
//   entering body t+1: [A(t+1)8, W(t+2)2]. Induction holds.
//   Tails: body NT-2 pre-barrier vmcnt(8); body NT-1 vmcnt(0).
// Ring: slot (t+2)&3 written during body t; laggard readers are in body t-1
// reading slot (t-1)&3, diff 3 mod 4 -> disjoint.

#define STAGE_W(slot, kt) do {                                                         \
    _Pragma("unroll")                                                                  \
    for (int i_ = 0; i_ < 2; ++i_) {                                                   \
        __builtin_amdgcn_global_load_lds(                                              \
            (const __attribute__((address_space(1))) unsigned int*)(wsrc[i_] + (size_t)(kt) * 64), \
            (__attribute__((address_space(3))) unsigned int*)(&wbuf[(slot)][wldsoff[i_]]), \
            16, 0, 0);                                                                 \
    } } while (0)

#define LOAD_A(dst, kt) do {                                                           \
    _Pragma("unroll")                                                                  \
    for (int m_ = 0; m_ < 4; ++m_)                                                     \
      _Pragma("unroll")                                                                \
      for (int s_ = 0; s_ < 2; ++s_)                                                   \
        dst[m_*2+s_] = *(const bf16x8*)(ap[m_] + (size_t)(kt) * 64 + s_ * 32);         \
    } while (0)

#define COMPUTE(AUSE, T_) do {                                                         \
    const float* wb_ = &wbuf[(T_) & 3][0];                                             \
    _Pragma("unroll")                                                                  \
    for (int s_ = 0; s_ < 2; ++s_) {                                                   \
      bf16x8 bfr[2];                                                                   \
      _Pragma("unroll")                                                                \
      for (int n_ = 0; n_ < 2; ++n_) {                                                 \
        int row_ = n_ * 16 + lr;                                                       \
        int x_   = row_ & 15;                                                          \
        int g0_  = s_ * 8 + lg * 2;                                                    \
        float4 lo_ = *(const float4*)&wb_[row_ * 64 + (((g0_    ) ^ x_) << 2)];        \
        float4 hi_ = *(const float4*)&wb_[row_ * 64 + (((g0_ + 1) ^ x_) << 2)];        \
        bf16x8 t_;                                                                     \
        t_[0]=bfc(lo_.x); t_[1]=bfc(lo_.y); t_[2]=bfc(lo_.z); t_[3]=bfc(lo_.w);        \
        t_[4]=bfc(hi_.x); t_[5]=bfc(hi_.y); t_[6]=bfc(hi_.z); t_[7]=bfc(hi_.w);        \
        bfr[n_] = t_;                                                                  \
      }                                                                                \
      _Pragma("unroll")                                                                \
      for (int m_ = 0; m_ < 4; ++m_)                                                   \
        _Pragma("unroll")                                                              \
        for (int n_ = 0; n_ < 2; ++n_)                                                 \
          acc[m_][n_] = __builtin_amdgcn_mfma_f32_16x16x32_bf16(                       \
              AUSE[m_*2+s_], bfr[n_], acc[m_][n_], 0, 0, 0);                           \
    } } while (0)

#define BODY(T_, AUSE, ALOAD, ISSA, ISSW, PREBAR) do {                                 \
    if (ISSA) LOAD_A(ALOAD, (T_) + 1);                                                 \
    if (ISSW) STAGE_W(((T_) + 2) & 3, (T_) + 2);                                       \
    COMPUTE(AUSE, T_);                                                                 \
    asm volatile("s_waitcnt " PREBAR "\n\ts_barrier" ::: "memory");                    \
    } while (0)

__global__ __launch_bounds__(256, 4) void gemm_kernel(
    const __hip_bfloat16* __restrict__ vbf,   // [256][32768] bf16
    const float* __restrict__ W,              // [4096][32768] fp32
    float* __restrict__ part,                 // [KS][256][4096] fp32
    int KS, int NT)                           // NT = (K_/KS)/64, even, >= 4
{
    __shared__ __align__(16) float wbuf[4][32 * 64];   // 4 x 8 KB fp32 ring

    const int tid  = threadIdx.x;
    const int wid  = tid >> 6;    // wave = M-group (64 rows)
    const int lane = tid & 63;
    const int lr   = lane & 15;
    const int lg   = lane >> 4;

    const int bid   = blockIdx.x;
    const int sidx  = bid % KS;   // == XCD id when KS==8
    const int ht    = bid / KS;
    const int h0    = ht * 32;
    const int kbase = sidx * (NT * 64);

    // W staging: LDS linear granule (row, g') holds global granule g = g' ^ (row&15)
    const float* wsrc[2];
    int wldsoff[2];
    #pragma unroll
    for (int i = 0; i < 2; ++i) {
        int f   = i * 256 + tid;
        int row = f >> 4;        // 0..31
        int gl  = f & 15;        // linear 16B granule in row
        int g   = gl ^ (row & 15);
        wsrc[i]    = W + (size_t)(h0 + row) * K_ + kbase + g * 4;
        wldsoff[i] = (i * 256 + wid * 64) * 4;   // float idx, wave-uniform base
    }

    // A: this wave owns rows wid*64 .. wid*64+63
    const __hip_bfloat16* ap[4];
    #pragma unroll
    for (int m = 0; m < 4; ++m)
        ap[m] = vbf + (size_t)(wid * 64 + m * 16 + lr) * K_ + kbase + lg * 8;

    f32x4 acc[4][2];
    #pragma unroll
    for (int m = 0; m < 4; ++m)
        #pragma unroll
        for (int n = 0; n < 2; ++n)
            acc[m][n] = (f32x4)(0.0f);

    bf16x8 aA[8], aB[8];

    // Prologue: A(0), W(0), W(1); drain A(0)+W(0), keep W(1) in flight.
    LOAD_A(aA, 0);
    STAGE_W(0, 0);
    STAGE_W(1, 1);
    asm volatile("s_waitcnt vmcnt(2)\n\ts_barrier" ::: "memory");

    for (int t = 0; t < NT - 2; t += 2) {
        BODY(t,     aA, aB, true, true, "vmcnt(10)");
        BODY(t + 1, aB, aA, true, true, "vmcnt(10)");
    }
    BODY(NT - 2, aA, aB, true,  false, "vmcnt(8)");
    BODY(NT - 1, aB, aA, false, false, "vmcnt(0)");

    // Epilogue: C/D layout col=lane&15 (=h), row=(lane>>4)*4+reg (=b)
    float* pout = part + (size_t)sidx * ((size_t)B_ * H_) + h0;
    #pragma unroll
    for (int m = 0; m < 4; ++m)
        #pragma unroll
        for (int n = 0; n < 2; ++n)
            #pragma unroll
            for (int j = 0; j < 4; ++j) {
                int brow = wid * 64 + m * 16 + lg * 4 + j;
                int hcol = n * 16 + lr;
                pout[(size_t)brow * H_ + hcol] = acc[m][n][j];
            }
}

// ---------------- Kernel C: reduce splits + b_h, softplus, sum over H, + vt ----------------
__global__ __launch_bounds__(256) void reduce_kernel(
    const float* __restrict__ part, const float* __restrict__ bh,
    const float* __restrict__ vt, float* __restrict__ out, int KS)
{
    const int b = blockIdx.x;
    const int t = threadIdx.x;
    float sp = 0.f;
    const float* pb = part + (size_t)b * H_;
    for (int h = t * 4; h < H_; h += 256 * 4) {
        float4 l = *(const float4*)(bh + h);
        for (int s = 0; s < KS; ++s) {
            float4 p = *(const float4*)(pb + (size_t)s * B_ * H_ + h);
            l.x += p.x; l.y += p.y; l.z += p.z; l.w += p.w;
        }
        sp += softplus_f(l.x) + softplus_f(l.y) + softplus_f(l.z) + softplus_f(l.w);
    }
    __shared__ float sm[256];
    sm[t] = sp;
    __syncthreads();
    for (int r = 128; r > 0; r >>= 1) {
        if (t < r) sm[t] += sm[t + r];
        __syncthreads();
    }
    if (t == 0) out[b] = sm[0] + vt[b];
}

extern "C" void kernel_launch(void* const* d_in, const int* in_sizes, int n_in,
                              void* d_out, int out_size, void* d_ws, size_t ws_size,
                              hipStream_t stream)
{
    const float* v  = (const float*)d_in[0];
    const float* W  = (const float*)d_in[1];
    const float* bh = (const float*)d_in[2];
    const float* bv = (const float*)d_in[3];
    float* out = (float*)d_out;

    char* ws = (char*)d_ws;
    const size_t vbf_bytes = (size_t)B_ * K_ * sizeof(__hip_bfloat16);  // 16 MB
    __hip_bfloat16* vbf = (__hip_bfloat16*)ws;

    int KS = 8;                                   // shrink if workspace is small
    while (KS > 1 && vbf_bytes + (size_t)KS * B_ * H_ * 4 + 1024 > ws_size) KS >>= 1;

    float* part = (float*)(ws + vbf_bytes);                                  // KS*4 MB
    float* vt   = (float*)(ws + vbf_bytes + (size_t)KS * B_ * H_ * 4);       // 1 KB

    prep_kernel<<<B_, 256, 0, stream>>>(v, bv, vbf, vt);
    const int NT = (K_ / KS) / 64;                // 64 for KS=8 (even, >=4)
    gemm_kernel<<<(H_ / 32) * KS, 256, 0, stream>>>(vbf, W, part, KS, NT);
    reduce_kernel<<<B_, 256, 0, stream>>>(part, bh, vt, out, KS);
}

// Round 14
// 221.074 us; speedup vs baseline: 1.3983x; 1.3983x over previous
//
#include <hip/hip_runtime.h>
#include <hip/hip_bf16.h>
#include <stdint.h>

#define B_ 256
#define H_ 4096
#define K_ 32768   // V*N = 1024*32

typedef __attribute__((ext_vector_type(8))) short bf16x8;
typedef __attribute__((ext_vector_type(4))) float f32x4;

__device__ __forceinline__ unsigned short f2bf(float x) {
    union { float f; unsigned int u; } c; c.f = x;
    unsigned int r = c.u + 0x7FFFu + ((c.u >> 16) & 1u);  // RNE
    return (unsigned short)(r >> 16);
}

__device__ __forceinline__ short bfc(float x) {
    __hip_bfloat16 h = __float2bfloat16(x);
    union { __hip_bfloat16 h; short s; } c; c.h = h;
    return c.s;
}

__device__ __forceinline__ float softplus_f(float x) {
    return fmaxf(x, 0.0f) + log1pf(expf(-fabsf(x)));
}

// ---------------- Kernel A: v fp32->bf16 + vt[b] = dot(v[b,:], b_v) ----------------
__global__ __launch_bounds__(256) void prep_kernel(
    const float* __restrict__ v, const float* __restrict__ bv,
    __hip_bfloat16* __restrict__ vbf, float* __restrict__ vt)
{
    const int b = blockIdx.x;
    const int t = threadIdx.x;
    const float* vr = v + (size_t)b * K_;
    unsigned short* dr = (unsigned short*)(vbf + (size_t)b * K_);
    float acc = 0.f;
    for (int i = t * 8; i < K_; i += 256 * 8) {
        float4 x0 = *(const float4*)(vr + i);
        float4 x1 = *(const float4*)(vr + i + 4);
        float4 b0 = *(const float4*)(bv + i);
        float4 b1 = *(const float4*)(bv + i + 4);
        acc += x0.x*b0.x + x0.y*b0.y + x0.z*b0.z + x0.w*b0.w
             + x1.x*b1.x + x1.y*b1.y + x1.z*b1.z + x1.w*b1.w;
        ushort4 u0, u1;
        u0.x = f2bf(x0.x); u0.y = f2bf(x0.y); u0.z = f2bf(x0.z); u0.w = f2bf(x0.w);
        u1.x = f2bf(x1.x); u1.y = f2bf(x1.y); u1.z = f2bf(x1.z); u1.w = f2bf(x1.w);
        *(ushort4*)(dr + i)     = u0;
        *(ushort4*)(dr + i + 4) = u1;
    }
    __shared__ float sm[256];
    sm[t] = acc;
    __syncthreads();
    for (int s = 128; s > 0; s >>= 1) {
        if (t < s) sm[t] += sm[t + s];
        __syncthreads();
    }
    if (t == 0) vt[b] = sm[0];
}

// ---------------- Kernel B: producer-consumer GEMM, BM=256 BN=128 BK=256 ----------------
// DRAM-page-locality fix: W read in 1 KB-contiguous per-row visits (BK=256 fp32),
// vs 256 B in all prior rounds (those converged to ~3 TB/s W delivery = page-
// activation bound). Depth-2 LDS ring of [128 rows][256 bf16] tiles (128 KB).
// 640 threads: 8 consumers (32M x 128N each; per body 8 phases x {2 A-loads,
// 8 ds_read_b128, 16 MFMA}; compiler-exact waits; 1 barrier/body) + 2 producers
// (chunks = 16 rows x 1 KB/row; 4-deep chunk pipeline, vmcnt(6) steady,
// descending tail; cvt->bf16; XOR-swizzled conflict-free ds_write).
//
// Ring safety (1 barrier/body): body t consumer reads slot t&1 (data consumed by
// MFMAs before CBAR(t)); producer writes slot (t+2)&1 = t&1 only AFTER barrier t.
// Tile t+1 fully written + lgkmcnt(0) before barrier t. Barriers: NT+1 both roles.
//
// Producer chunk pipeline (2 loads/chunk): in-flight 4 chunks = 8 loads;
// vmcnt(6) drains exactly the oldest chunk. Tail: vmcnt(6),(4),(2),(0).

#define NCONS 8
#define VMW(N)  asm volatile("s_waitcnt vmcnt(" #N ")" ::: "memory")
#define PBAR()  asm volatile("s_waitcnt lgkmcnt(0)\n\ts_barrier" ::: "memory")
#define CBAR()  asm volatile("s_barrier" ::: "memory")

// Producer: issue chunk (tile TT, within-tile chunk CC): rows (CC>>2)*16+rsub,
// cols TT*256 + (CC&3)*64 + l8*8 (8 floats = 2 dwordx4, 1 KB/row across CC&3).
#define P_ISS(BUF, TT, CC) do {                                                        \
    const float* p_ = wlb + (size_t)((CC) >> 2) * (16 * (size_t)K_)                    \
                          + (size_t)(TT) * 256 + ((CC) & 3) * 64;                      \
    BUF[0] = *(const float4*)p_;                                                       \
    BUF[1] = *(const float4*)(p_ + 4);                                                 \
    } while (0)

// Producer: cvt + swizzled write of one chunk into ring slot (byte-base SLOT_).
#define P_WR(BUF, SLOT_, CC) do {                                                      \
    int r_ = (((CC) >> 2) & 7) * 16 + rsub;                                            \
    int g_ = ((((CC) & 3) * 8 + l8) ^ r7);                                             \
    bf16x8 u_;                                                                         \
    u_[0]=bfc(BUF[0].x); u_[1]=bfc(BUF[0].y); u_[2]=bfc(BUF[0].z); u_[3]=bfc(BUF[0].w);\
    u_[4]=bfc(BUF[1].x); u_[5]=bfc(BUF[1].y); u_[6]=bfc(BUF[1].z); u_[7]=bfc(BUF[1].w);\
    *(bf16x8*)&wtile[(SLOT_) + r_ * 256 + g_ * 8] = u_;                                \
    } while (0)

__global__ __launch_bounds__(640, 4) void gemm_kernel(
    const __hip_bfloat16* __restrict__ vbf,   // [256][32768] bf16
    const float* __restrict__ W,              // [4096][32768] fp32
    float* __restrict__ part,                 // [KS][256][4096] fp32
    int KS, int NT)                           // NT = (K_/KS)/256, >= 3
{
    __shared__ __align__(16) unsigned short wtile[2 * 128 * 256];  // 128 KB ring

    const int tid  = threadIdx.x;
    const int wid  = tid >> 6;
    const int lane = tid & 63;
    const int lr   = lane & 15;
    const int lg   = lane >> 4;

    const int bid   = blockIdx.x;
    const int sidx  = bid % KS;
    const int ht    = bid / KS;
    const int h0    = ht * 128;
    const int kbase = sidx * (NT * 256);

    if (wid < NCONS) {
        // ---------------- consumer: 32 M-rows x 128 N-cols ----------------
        const __hip_bfloat16* ap0 = vbf + (size_t)(wid * 32 + lr) * K_ + kbase + lg * 8;
        const __hip_bfloat16* ap1 = ap0 + (size_t)16 * K_;

        f32x4 acc[2][8];
        #pragma unroll
        for (int m = 0; m < 2; ++m)
            #pragma unroll
            for (int n = 0; n < 8; ++n)
                acc[m][n] = (f32x4)(0.0f);

        CBAR();   // prologue: tile 0 staged

        for (int t = 0; t < NT; ++t) {
            const unsigned short* wb = &wtile[(t & 1) * 32768];
            const size_t koff = (size_t)t * 256;
            #pragma unroll
            for (int s = 0; s < 8; ++s) {
                bf16x8 a0 = *(const bf16x8*)(ap0 + koff + s * 32);
                bf16x8 a1 = *(const bf16x8*)(ap1 + koff + s * 32);
                #pragma unroll
                for (int q = 0; q < 2; ++q) {
                    bf16x8 bfr[4];
                    #pragma unroll
                    for (int n = 0; n < 4; ++n) {
                        int row = (q * 4 + n) * 16 + lr;
                        int g   = (s * 4 + lg) ^ (lr & 7);   // row&7 == lr&7
                        bfr[n] = *(const bf16x8*)&wb[row * 256 + g * 8];
                    }
                    #pragma unroll
                    for (int n = 0; n < 4; ++n) {
                        acc[0][q*4+n] = __builtin_amdgcn_mfma_f32_16x16x32_bf16(
                            a0, bfr[n], acc[0][q*4+n], 0, 0, 0);
                        acc[1][q*4+n] = __builtin_amdgcn_mfma_f32_16x16x32_bf16(
                            a1, bfr[n], acc[1][q*4+n], 0, 0, 0);
                    }
                }
            }
            CBAR();
        }

        // Epilogue: C/D layout col=lane&15 (=h), row=(lane>>4)*4+reg (=b)
        float* pout = part + (size_t)sidx * ((size_t)B_ * H_) + h0;
        #pragma unroll
        for (int m = 0; m < 2; ++m)
            #pragma unroll
            for (int n = 0; n < 8; ++n)
                #pragma unroll
                for (int j = 0; j < 4; ++j) {
                    int brow = wid * 32 + m * 16 + lg * 4 + j;
                    int hcol = n * 16 + lr;
                    pout[(size_t)brow * H_ + hcol] = acc[m][n][j];
                }
    } else {
        // ---------------- producer: [128 rows][256 cols fp32] per body ----------------
        const int gl   = (wid - NCONS) * 64 + lane;   // 0..127
        const int rsub = gl >> 3;                     // 0..15 (row within chunk)
        const int l8   = gl & 7;                      // 8-float slot within 64-col group
        const int r7   = rsub & 7;
        const float* wlb = W + (size_t)(h0 + rsub) * K_ + kbase + l8 * 8;

        float4 buf0[2], buf1[2], buf2[2], buf3[2];

        // Warm pipeline: chunks 0..3 of tile 0.
        P_ISS(buf0, 0, 0); P_ISS(buf1, 0, 1); P_ISS(buf2, 0, 2); P_ISS(buf3, 0, 3);

        // Prologue: write all 32 chunks of tile 0 -> slot 0; issues run 4 ahead.
        #pragma unroll
        for (int c = 0; c < 32; ++c) {
            VMW(6);
            if ((c & 3) == 0) { P_WR(buf0, 0, c); if (c < 28) P_ISS(buf0, 0, c+4); else P_ISS(buf0, 1, c-28); }
            if ((c & 3) == 1) { P_WR(buf1, 0, c); if (c < 28) P_ISS(buf1, 0, c+4); else P_ISS(buf1, 1, c-28); }
            if ((c & 3) == 2) { P_WR(buf2, 0, c); if (c < 28) P_ISS(buf2, 0, c+4); else P_ISS(buf2, 1, c-28); }
            if ((c & 3) == 3) { P_WR(buf3, 0, c); if (c < 28) P_ISS(buf3, 0, c+4); else P_ISS(buf3, 1, c-28); }
        }
        PBAR();

        // Steady bodies t=0..NT-3: write tile t+1 -> slot (t+1)&1.
        for (int t = 0; t < NT - 2; ++t) {
            const int slot = ((t + 1) & 1) * 32768;
            #pragma unroll
            for (int c = 0; c < 32; ++c) {
                VMW(6);
                if ((c & 3) == 0) { P_WR(buf0, slot, c); if (c < 28) P_ISS(buf0, t+1, c+4); else P_ISS(buf0, t+2, c-28); }
                if ((c & 3) == 1) { P_WR(buf1, slot, c); if (c < 28) P_ISS(buf1, t+1, c+4); else P_ISS(buf1, t+2, c-28); }
                if ((c & 3) == 2) { P_WR(buf2, slot, c); if (c < 28) P_ISS(buf2, t+1, c+4); else P_ISS(buf2, t+2, c-28); }
                if ((c & 3) == 3) { P_WR(buf3, slot, c); if (c < 28) P_ISS(buf3, t+1, c+4); else P_ISS(buf3, t+2, c-28); }
            }
            PBAR();
        }

        // Final producing body (t = NT-2): write tile NT-1; issues end, tail drains.
        {
            const int slot = ((NT - 1) & 1) * 32768;
            #pragma unroll
            for (int c = 0; c < 28; ++c) {
                VMW(6);
                if ((c & 3) == 0) { P_WR(buf0, slot, c); P_ISS(buf0, NT-1, c+4); }
                if ((c & 3) == 1) { P_WR(buf1, slot, c); P_ISS(buf1, NT-1, c+4); }
                if ((c & 3) == 2) { P_WR(buf2, slot, c); P_ISS(buf2, NT-1, c+4); }
                if ((c & 3) == 3) { P_WR(buf3, slot, c); P_ISS(buf3, NT-1, c+4); }
            }
            VMW(6); P_WR(buf0, slot, 28);
            VMW(4); P_WR(buf1, slot, 29);
            VMW(2); P_WR(buf2, slot, 30);
            VMW(0); P_WR(buf3, slot, 31);
            PBAR();
        }
        PBAR();   // matches consumers' final body barrier
    }
}

// ---------------- Kernel C: reduce splits + b_h, softplus, sum over H, + vt ----------------
__global__ __launch_bounds__(256) void reduce_kernel(
    const float* __restrict__ part, const float* __restrict__ bh,
    const float* __restrict__ vt, float* __restrict__ out, int KS)
{
    const int b = blockIdx.x;
    const int t = threadIdx.x;
    float sp = 0.f;
    const float* pb = part + (size_t)b * H_;
    for (int h = t * 4; h < H_; h += 256 * 4) {
        float4 l = *(const float4*)(bh + h);
        for (int s = 0; s < KS; ++s) {
            float4 p = *(const float4*)(pb + (size_t)s * B_ * H_ + h);
            l.x += p.x; l.y += p.y; l.z += p.z; l.w += p.w;
        }
        sp += softplus_f(l.x) + softplus_f(l.y) + softplus_f(l.z) + softplus_f(l.w);
    }
    __shared__ float sm[256];
    sm[t] = sp;
    __syncthreads();
    for (int r = 128; r > 0; r >>= 1) {
        if (t < r) sm[t] += sm[t + r];
        __syncthreads();
    }
    if (t == 0) out[b] = sm[0] + vt[b];
}

extern "C" void kernel_launch(void* const* d_in, const int* in_sizes, int n_in,
                              void* d_out, int out_size, void* d_ws, size_t ws_size,
                              hipStream_t stream)
{
    const float* v  = (const float*)d_in[0];
    const float* W  = (const float*)d_in[1];
    const float* bh = (const float*)d_in[2];
    const float* bv = (const float*)d_in[3];
    float* out = (float*)d_out;

    char* ws = (char*)d_ws;
    const size_t vbf_bytes = (size_t)B_ * K_ * sizeof(__hip_bfloat16);  // 16 MB
    __hip_bfloat16* vbf = (__hip_bfloat16*)ws;

    int KS = 16;                                  // shrink if workspace is small
    while (KS > 1 && vbf_bytes + (size_t)KS * B_ * H_ * 4 + 1024 > ws_size) KS >>= 1;

    float* part = (float*)(ws + vbf_bytes);                                  // KS*4 MB
    float* vt   = (float*)(ws + vbf_bytes + (size_t)KS * B_ * H_ * 4);       // 1 KB

    prep_kernel<<<B_, 256, 0, stream>>>(v, bv, vbf, vt);
    const int NT = (K_ / KS) / 256;               // 8 for KS=16 (>= 3)
    gemm_kernel<<<(H_ / 128) * KS, 640, 0, stream>>>(vbf, W, part, KS, NT);
    reduce_kernel<<<B_, 256, 0, stream>>>(part, bh, vt, out, KS);
}